// Round 7
// baseline (379.152 us; speedup 1.0000x reference)
//
#include <hip/hip_runtime.h>
#include <hip/hip_fp16.h>

#define N_NODES   100000
#define N_EDGES   3200000
#define NUM_GRAPHS 1024
#define F_IN      128
#define EMB       32

#define NRANGE    4
#define RANGE_SZ  25000                    // fp16 rows: 25000*64B = 1.6 MB slice per phase
#define NKEY      (N_NODES * NRANGE)       // 400000 CSR keys

#define NGROUP    256                      // dst buckets
#define GROUP_SZ  391                      // 256*391 = 100096 >= N
#define BCAP      13824                    // mean 12512 + ~11.7 sigma
#define FB        1024                     // fill block threads
#define FILL_ITER 14                       // ceil(BCAP/FB)

#define PART_TILE 8192
#define PART_THREADS 512
#define PART_NB   ((N_EDGES + PART_TILE - 1) / PART_TILE)   // 391

#define NTILE     3125                     // 100000/32 exact
#define NBLK      1563                     // ceil(3125/2): 1562 blocks x2 tiles + 1 x1 (no tail)
#define TMAX      2                        // 8 blocks/CU capacity -> all 1563 co-resident
#define LCAP      1408                     // per-tile col LDS cap (mean 1024, +12 sigma)

// 8-byte half4 payload: node row = 8 quads x 8 B = 64 B = one L2 line per edge
struct __align__(8) h4 { __half2 a, b; };
__device__ inline float4 h4tof4(h4 v) {
    float2 fa = __half22float2(v.a), fb = __half22float2(v.b);
    return make_float4(fa.x, fa.y, fb.x, fb.y);
}
__device__ inline h4 f4toh4(float4 v) {
    h4 r; r.a = __floats2half2_rn(v.x, v.y); r.b = __floats2half2_rn(v.z, v.w); return r;
}

// ---- tiny init: zero bucket counters; rp2 sentinel ----
__global__ void init_k(int* __restrict__ bucketCnt, int* __restrict__ rp2) {
    int i = threadIdx.x;
    if (i < NGROUP) bucketCnt[i] = 0;
    if (i == 0) rp2[NKEY] = N_EDGES;
}

// ---- partition edges into 256 dst-buckets, packed 4B, coalesced nt writes ----
__global__ __launch_bounds__(PART_THREADS) void partition_k(const int* __restrict__ src,
                                                            const int* __restrict__ dst,
                                                            int* __restrict__ bucketCnt,
                                                            unsigned* __restrict__ bEdges) {
    __shared__ unsigned stage[PART_TILE];          // 32 KB
    __shared__ unsigned char bucketOf[PART_TILE];  // 8 KB
    __shared__ int hist[NGROUP];
    __shared__ int lbase[NGROUP + 1];
    __shared__ int gbase[NGROUP];
    __shared__ int sc[NGROUP];
    int t = threadIdx.x;
    int base = blockIdx.x * PART_TILE;
    for (int k = t; k < NGROUP; k += PART_THREADS) hist[k] = 0;
    __syncthreads();
    unsigned val[16]; int bk[16], rk[16];
#pragma unroll
    for (int i = 0; i < 16; ++i) {
        int e = base + i * PART_THREADS + t;
        bk[i] = -1;
        if (e < N_EDGES) {
            unsigned s = (unsigned)__builtin_nontemporal_load(src + e);
            unsigned d = (unsigned)__builtin_nontemporal_load(dst + e);
            int b = (int)(d / GROUP_SZ);
            val[i] = ((d - (unsigned)b * GROUP_SZ) << 17) | s;
            bk[i] = b;
            rk[i] = atomicAdd(&hist[b], 1);            // LDS atomic
        }
    }
    __syncthreads();
    if (t < NGROUP) sc[t] = hist[t];
    __syncthreads();
    for (int off = 1; off < NGROUP; off <<= 1) {
        int v = 0;
        if (t < NGROUP) v = sc[t] + ((t >= off) ? sc[t - off] : 0);
        __syncthreads();
        if (t < NGROUP) sc[t] = v;
        __syncthreads();
    }
    if (t < NGROUP) {
        lbase[t] = sc[t] - hist[t];
        if (hist[t] > 0) gbase[t] = atomicAdd(&bucketCnt[t], hist[t]);
        if (t == NGROUP - 1) lbase[NGROUP] = sc[t];
    }
    __syncthreads();
#pragma unroll
    for (int i = 0; i < 16; ++i)
        if (bk[i] >= 0) {
            int j = lbase[bk[i]] + rk[i];
            stage[j] = val[i];
            bucketOf[j] = (unsigned char)bk[i];
        }
    __syncthreads();
    int total = lbase[NGROUP];
    for (int j = t; j < total; j += PART_THREADS) {
        int b = bucketOf[j];                           // direct lookup
        int off = gbase[b] + (j - lbase[b]);
        if (off < BCAP) __builtin_nontemporal_store(stage[j], &bEdges[(size_t)b * BCAP + off]);
    }
}

// ---- one-off: exclusive scan of 256 bucket counts -> global bucketBase ----
__global__ __launch_bounds__(256) void bucketbase_k(const int* __restrict__ bucketCnt,
                                                    int* __restrict__ bucketBase) {
    __shared__ int l[256];
    int t = threadIdx.x;
    int c = bucketCnt[t]; if (c > BCAP) c = BCAP;
    l[t] = c;
    __syncthreads();
    for (int off = 1; off < 256; off <<= 1) {
        int v = l[t] + ((t >= off) ? l[t - off] : 0);
        __syncthreads();
        l[t] = v;
        __syncthreads();
    }
    bucketBase[t] = l[t] - c;                          // exclusive
}

// ---- per-bucket LDS counting sort with (node, src-range) keys ----
__global__ __launch_bounds__(FB) void fill_k(const unsigned* __restrict__ bEdges,
                                             const int* __restrict__ bucketCnt,
                                             const int* __restrict__ bucketBase,
                                             int* __restrict__ rp2,
                                             float* __restrict__ dinv,
                                             int* __restrict__ col) {
    __shared__ int cur[GROUP_SZ * 4];      // 1564 key cursors
    __shared__ int nodesum[512];
    __shared__ unsigned lout[BCAP];        // 55.3 KB staging
    int b = blockIdx.x, t = threadIdx.x;
    int colBase = bucketBase[b];

    int nb = N_NODES - b * GROUP_SZ; if (nb > GROUP_SZ) nb = GROUP_SZ;
    int nk = nb * 4;
    for (int k = t; k < nk; k += FB) cur[k] = 0;
    __syncthreads();

    int cnt = bucketCnt[b]; if (cnt > BCAP) cnt = BCAP;
    const unsigned* be = bEdges + (size_t)b * BCAP;
    unsigned val[FILL_ITER];
#pragma unroll
    for (int i = 0; i < FILL_ITER; ++i) {
        int idx = i * FB + t;
        val[i] = 0xFFFFFFFFu;
        if (idx < cnt) {
            unsigned v = __builtin_nontemporal_load(be + idx);
            val[i] = v;
            unsigned key = (v >> 17) * NRANGE + (v & 0x1FFFFu) / RANGE_SZ;
            atomicAdd(&cur[key], 1);                   // LDS histogram
        }
    }
    __syncthreads();

    int h0 = 0, h1 = 0, h2 = 0, h3 = 0;
    if (t < nb) {
        h0 = cur[t * 4]; h1 = cur[t * 4 + 1]; h2 = cur[t * 4 + 2]; h3 = cur[t * 4 + 3];
        int dsum = h0 + h1 + h2 + h3;
        nodesum[t] = dsum;
        dinv[b * GROUP_SZ + t] = rsqrtf((float)(dsum + 1));
    } else if (t < 512) nodesum[t] = 0;
    __syncthreads();
    for (int off = 1; off < 512; off <<= 1) {
        int v = 0;
        if (t < 512) v = nodesum[t] + ((t >= off) ? nodesum[t - off] : 0);
        __syncthreads();
        if (t < 512) nodesum[t] = v;
        __syncthreads();
    }
    if (t < nb) {
        int p0 = (t > 0) ? nodesum[t - 1] : 0;
        int p1 = p0 + h0, p2 = p1 + h1, p3 = p2 + h2;
        int kb = (b * GROUP_SZ + t) * 4;
        int4 w; w.x = colBase + p0; w.y = colBase + p1; w.z = colBase + p2; w.w = colBase + p3;
        *(int4*)(rp2 + kb) = w;
        cur[t * 4] = p0; cur[t * 4 + 1] = p1; cur[t * 4 + 2] = p2; cur[t * 4 + 3] = p3;
    }
    __syncthreads();

#pragma unroll
    for (int i = 0; i < FILL_ITER; ++i) {
        unsigned v = val[i];
        if (v != 0xFFFFFFFFu) {
            unsigned key = (v >> 17) * NRANGE + (v & 0x1FFFFu) / RANGE_SZ;
            int slot = atomicAdd(&cur[key], 1);
            lout[slot] = v & 0x1FFFFu;
        }
    }
    __syncthreads();

    for (int i = t; i < cnt; i += FB)
        __builtin_nontemporal_store((int)lout[i], col + colBase + i);
}

// ---- layer 0 transform, register-blocked; writes fp16 payload ----
__global__ __launch_bounds__(256) void transform0_k(const float* __restrict__ x,
                                                    const float* __restrict__ W0,
                                                    const float* __restrict__ dinv,
                                                    h4* __restrict__ tmph) {
    int i = blockIdx.x * blockDim.x + threadIdx.x;   // 100000 threads
    if (i >= (N_NODES / 8) * 8) return;
    int gid = i >> 3, q = i & 7;
    int n0 = gid * 8;
    const float* wq = W0 + q * 4;
    float4 acc[8];
#pragma unroll
    for (int j = 0; j < 8; ++j) acc[j] = make_float4(0.f, 0.f, 0.f, 0.f);
#pragma unroll 2
    for (int kc = 0; kc < F_IN / 4; ++kc) {
        float4 w0 = *(const float4*)(wq + (kc * 4 + 0) * EMB);
        float4 w1 = *(const float4*)(wq + (kc * 4 + 1) * EMB);
        float4 w2 = *(const float4*)(wq + (kc * 4 + 2) * EMB);
        float4 w3 = *(const float4*)(wq + (kc * 4 + 3) * EMB);
#pragma unroll
        for (int j = 0; j < 8; ++j) {
            float4 xv = *(const float4*)(x + (long long)(n0 + j) * F_IN + kc * 4);
            acc[j].x += xv.x * w0.x; acc[j].y += xv.x * w0.y; acc[j].z += xv.x * w0.z; acc[j].w += xv.x * w0.w;
            acc[j].x += xv.y * w1.x; acc[j].y += xv.y * w1.y; acc[j].z += xv.y * w1.z; acc[j].w += xv.y * w1.w;
            acc[j].x += xv.z * w2.x; acc[j].y += xv.z * w2.y; acc[j].z += xv.z * w2.z; acc[j].w += xv.z * w2.w;
            acc[j].x += xv.w * w3.x; acc[j].y += xv.w * w3.y; acc[j].z += xv.w * w3.z; acc[j].w += xv.w * w3.w;
        }
    }
#pragma unroll
    for (int j = 0; j < 8; ++j) {
        float dn = dinv[n0 + j];
        acc[j].x *= dn; acc[j].y *= dn; acc[j].z *= dn; acc[j].w *= dn;
        tmph[(n0 + j) * 8 + q] = f4toh4(acc[j]);
    }
}

// ---- multi-tile gather, fp16 payload: 1563 blocks (6.1/CU avg, 8/CU capacity,
// ALL co-resident at t=0), each owns 1-2 tiles (near-perfect balance, no tail).
// One edge = one 64B L2 line (8 q-lanes x 8B contiguous). Accumulate fp32.
// hx (epilogue h-exchange) is ALIASED onto colS (dead after r-loop).
// FUSE=1: out = (leaky(agg*dinv+bias) @ W) * dinv    FUSE=0: out = leaky(agg*dinv+bias)
template <bool FUSE>
__global__ __launch_bounds__(256, 8) void gather_mt_k(const int* __restrict__ rp2,
                                                      const int* __restrict__ col,
                                                      const h4* __restrict__ inb,
                                                      const float* __restrict__ dinv,
                                                      const float* __restrict__ bias,
                                                      const float* __restrict__ W,
                                                      h4* __restrict__ outb) {
    __shared__ float4 Wl[256];                        // 4 KB
    __shared__ __align__(16) int colS[TMAX * LCAP];   // 11.3 KB; first 4.6 KB reused as hx
    __shared__ int begsS[TMAX][32][5];                // 1.3 KB (tile-local offsets, or global if overflow)

    int t = threadIdx.x;
    int blk = blockIdx.x;
    int q = t & 7, ln = t >> 3;

    if (FUSE) Wl[t] = ((const float4*)W)[t];

    // ---- staging: col spans + range pointers for this block's tiles ----
    int inLmask = 0;
#pragma unroll
    for (int tt = 0; tt < TMAX; ++tt) {
        int tile = blk + tt * NBLK;
        if (tile >= NTILE) continue;
        int S = rp2[tile * 128];
        int E = rp2[tile * 128 + 128];       // NKEY sentinel covers last tile
        int span = E - S;
        int inL = (span <= LCAP) ? 1 : 0;
        inLmask |= inL << tt;
        if (t < 160) {                       // 32 nodes x 5 pointers
            int node = t / 5, r = t % 5;
            int v = rp2[tile * 128 + node * 4 + r];
            begsS[tt][node][r] = inL ? (v - S) : v;
        }
        if (inL)
            for (int j = t; j < span; j += 256)
                colS[tt * LCAP + j] = __builtin_nontemporal_load(col + S + j);
    }
    __syncthreads();                         // covers colS, begsS, Wl

    float4 acc[TMAX];
#pragma unroll
    for (int tt = 0; tt < TMAX; ++tt) {
        int tile = blk + tt * NBLK;
        acc[tt] = (tile < NTILE) ? h4tof4(inb[tile * 256 + t])   // self-loop term
                                 : make_float4(0.f, 0.f, 0.f, 0.f);
    }

#pragma unroll 1
    for (int r = 0; r < NRANGE; ++r) {
#pragma unroll
        for (int tt = 0; tt < TMAX; ++tt) {
            int tile = blk + tt * NBLK;
            if (tile >= NTILE) continue;
            int k = begsS[tt][ln][r], end = begsS[tt][ln][r + 1];
            float4 a = acc[tt];
            if ((inLmask >> tt) & 1) {
                const int* cS = &colS[tt * LCAP];
                for (; k + 8 <= end; k += 8) {
                    int c0 = cS[k], c1 = cS[k + 1], c2 = cS[k + 2], c3 = cS[k + 3];
                    int c4 = cS[k + 4], c5 = cS[k + 5], c6 = cS[k + 6], c7 = cS[k + 7];
                    float4 v0 = h4tof4(inb[c0 * 8 + q]), v1 = h4tof4(inb[c1 * 8 + q]);
                    float4 v2 = h4tof4(inb[c2 * 8 + q]), v3 = h4tof4(inb[c3 * 8 + q]);
                    float4 v4 = h4tof4(inb[c4 * 8 + q]), v5 = h4tof4(inb[c5 * 8 + q]);
                    float4 v6 = h4tof4(inb[c6 * 8 + q]), v7 = h4tof4(inb[c7 * 8 + q]);
                    a.x += (v0.x + v1.x) + (v2.x + v3.x);
                    a.y += (v0.y + v1.y) + (v2.y + v3.y);
                    a.z += (v0.z + v1.z) + (v2.z + v3.z);
                    a.w += (v0.w + v1.w) + (v2.w + v3.w);
                    a.x += (v4.x + v5.x) + (v6.x + v7.x);
                    a.y += (v4.y + v5.y) + (v6.y + v7.y);
                    a.z += (v4.z + v5.z) + (v6.z + v7.z);
                    a.w += (v4.w + v5.w) + (v6.w + v7.w);
                }
                if (k + 4 <= end) {
                    int c0 = cS[k], c1 = cS[k + 1], c2 = cS[k + 2], c3 = cS[k + 3];
                    float4 v0 = h4tof4(inb[c0 * 8 + q]), v1 = h4tof4(inb[c1 * 8 + q]);
                    float4 v2 = h4tof4(inb[c2 * 8 + q]), v3 = h4tof4(inb[c3 * 8 + q]);
                    a.x += (v0.x + v1.x) + (v2.x + v3.x);
                    a.y += (v0.y + v1.y) + (v2.y + v3.y);
                    a.z += (v0.z + v1.z) + (v2.z + v3.z);
                    a.w += (v0.w + v1.w) + (v2.w + v3.w);
                    k += 4;
                }
                if (k < end) {                        // single masked-clamped iteration
                    int e1 = end - 1;
                    int i1 = min(k + 1, e1), i2 = min(k + 2, e1), i3 = min(k + 3, e1);
                    float m1 = (k + 1 < end) ? 1.f : 0.f;
                    float m2 = (k + 2 < end) ? 1.f : 0.f;
                    float m3 = (k + 3 < end) ? 1.f : 0.f;
                    int c0 = cS[k], c1 = cS[i1], c2 = cS[i2], c3 = cS[i3];
                    float4 v0 = h4tof4(inb[c0 * 8 + q]), v1 = h4tof4(inb[c1 * 8 + q]);
                    float4 v2 = h4tof4(inb[c2 * 8 + q]), v3 = h4tof4(inb[c3 * 8 + q]);
                    a.x += (v0.x + m1 * v1.x) + (m2 * v2.x + m3 * v3.x);
                    a.y += (v0.y + m1 * v1.y) + (m2 * v2.y + m3 * v3.y);
                    a.z += (v0.z + m1 * v1.z) + (m2 * v2.z + m3 * v3.z);
                    a.w += (v0.w + m1 * v1.w) + (m2 * v2.w + m3 * v3.w);
                }
            } else {                                  // overflow fallback: global col
                for (; k + 4 <= end; k += 4) {
                    int c0 = col[k], c1 = col[k + 1], c2 = col[k + 2], c3 = col[k + 3];
                    float4 v0 = h4tof4(inb[c0 * 8 + q]), v1 = h4tof4(inb[c1 * 8 + q]);
                    float4 v2 = h4tof4(inb[c2 * 8 + q]), v3 = h4tof4(inb[c3 * 8 + q]);
                    a.x += (v0.x + v1.x) + (v2.x + v3.x);
                    a.y += (v0.y + v1.y) + (v2.y + v3.y);
                    a.z += (v0.z + v1.z) + (v2.z + v3.z);
                    a.w += (v0.w + v1.w) + (v2.w + v3.w);
                }
                if (k < end) {
                    int e1 = end - 1;
                    int i1 = min(k + 1, e1), i2 = min(k + 2, e1), i3 = min(k + 3, e1);
                    float m1 = (k + 1 < end) ? 1.f : 0.f;
                    float m2 = (k + 2 < end) ? 1.f : 0.f;
                    float m3 = (k + 3 < end) ? 1.f : 0.f;
                    int c0 = col[k], c1 = col[i1], c2 = col[i2], c3 = col[i3];
                    float4 v0 = h4tof4(inb[c0 * 8 + q]), v1 = h4tof4(inb[c1 * 8 + q]);
                    float4 v2 = h4tof4(inb[c2 * 8 + q]), v3 = h4tof4(inb[c3 * 8 + q]);
                    a.x += (v0.x + m1 * v1.x) + (m2 * v2.x + m3 * v3.x);
                    a.y += (v0.y + m1 * v1.y) + (m2 * v2.y + m3 * v3.y);
                    a.z += (v0.z + m1 * v1.z) + (m2 * v2.z + m3 * v3.z);
                    a.w += (v0.w + m1 * v1.w) + (m2 * v2.w + m3 * v3.w);
                }
            }
            acc[tt] = a;
        }
    }

    __syncthreads();                         // all waves done with colS before hx aliases it
    float4* hx = (float4*)colS;              // 32 nodes x 8 quads, padded row=9 (4.5 KB < colS)

    // ---- epilogue per tile: bias + leaky, optional fused transform, write fp16 ----
#pragma unroll
    for (int tt = 0; tt < TMAX; ++tt) {
        int tile = blk + tt * NBLK;
        if (tile >= NTILE) continue;
        int n = tile * 32 + ln;
        float dn = dinv[n];
        float4 bb = ((const float4*)bias)[q];
        float4 rr;
        rr.x = acc[tt].x * dn + bb.x;
        rr.y = acc[tt].y * dn + bb.y;
        rr.z = acc[tt].z * dn + bb.z;
        rr.w = acc[tt].w * dn + bb.w;
        rr.x = rr.x > 0.f ? rr.x : 0.01f * rr.x;
        rr.y = rr.y > 0.f ? rr.y : 0.01f * rr.y;
        rr.z = rr.z > 0.f ? rr.z : 0.01f * rr.z;
        rr.w = rr.w > 0.f ? rr.w : 0.01f * rr.w;
        if (FUSE) {
            __builtin_amdgcn_wave_barrier();          // WAR vs previous tile's hx reads
            hx[ln * 9 + q] = rr;
            __builtin_amdgcn_wave_barrier();          // lanes of the wave are in lockstep
            float4 tq = make_float4(0.f, 0.f, 0.f, 0.f);
#pragma unroll
            for (int kq = 0; kq < 8; ++kq) {
                float4 hv = hx[ln * 9 + kq];
                float4 w0 = Wl[(kq * 4 + 0) * 8 + q];
                float4 w1 = Wl[(kq * 4 + 1) * 8 + q];
                float4 w2 = Wl[(kq * 4 + 2) * 8 + q];
                float4 w3 = Wl[(kq * 4 + 3) * 8 + q];
                tq.x += hv.x * w0.x; tq.y += hv.x * w0.y; tq.z += hv.x * w0.z; tq.w += hv.x * w0.w;
                tq.x += hv.y * w1.x; tq.y += hv.y * w1.y; tq.z += hv.y * w1.z; tq.w += hv.y * w1.w;
                tq.x += hv.z * w2.x; tq.y += hv.z * w2.y; tq.z += hv.z * w2.z; tq.w += hv.z * w2.w;
                tq.x += hv.w * w3.x; tq.y += hv.w * w3.y; tq.z += hv.w * w3.z; tq.w += hv.w * w3.w;
            }
            tq.x *= dn; tq.y *= dn; tq.z *= dn; tq.w *= dn;
            outb[tile * 256 + t] = f4toh4(tq);
        } else {
            outb[tile * 256 + t] = f4toh4(rr);
        }
    }
}

// ---- fused pool + head (batch_index sorted), fp16 input ----
__global__ __launch_bounds__(256) void pool_head_k(const __half* __restrict__ h,
                                                   const int* __restrict__ batch,
                                                   const float* __restrict__ Wout,
                                                   const float* __restrict__ bout,
                                                   float* __restrict__ out) {
    int g = blockIdx.x;
    __shared__ int sbeg, send;
    if (threadIdx.x == 0) {
        int lo = 0, hi = N_NODES;
        while (lo < hi) { int mid = (lo + hi) >> 1; if (batch[mid] < g) lo = mid + 1; else hi = mid; }
        sbeg = lo;
        hi = N_NODES;
        while (lo < hi) { int mid = (lo + hi) >> 1; if (batch[mid] < g + 1) lo = mid + 1; else hi = mid; }
        send = lo;
    }
    __syncthreads();
    int beg = sbeg, end = send;
    int t = threadIdx.x, c = t & 31, r = t >> 5;
    float m = -INFINITY;
    for (int n = beg + r; n < end; n += 8) m = fmaxf(m, __half2float(h[n * EMB + c]));
    __shared__ float red[256];
    red[t] = m;
    __syncthreads();
    if (t < 128) red[t] = fmaxf(red[t], red[t + 128]);
    __syncthreads();
    if (t < 64) red[t] = fmaxf(red[t], red[t + 64]);
    __syncthreads();
    if (t < 32) {
        m = fmaxf(red[t], red[t + 32]);
        out[NUM_GRAPHS + g * EMB + c] = m;
        float p = m * Wout[c];
#pragma unroll
        for (int o = 16; o > 0; o >>= 1) p += __shfl_xor(p, o, 32);
        if (c == 0) out[g] = p + bout[0];
    }
}

extern "C" void kernel_launch(void* const* d_in, const int* in_sizes, int n_in,
                              void* d_out, int out_size, void* d_ws, size_t ws_size,
                              hipStream_t stream) {
    const float* x     = (const float*)d_in[0];
    const int*   ei    = (const int*)d_in[1];
    const int*   src   = ei;
    const int*   dst   = ei + N_EDGES;
    const int*   batch = (const int*)d_in[2];
    const float* W0    = (const float*)d_in[3];
    const float* b0    = (const float*)d_in[4];
    const float* Ws    = (const float*)d_in[5];
    const float* bs    = (const float*)d_in[6];
    const float* Wout  = (const float*)d_in[7];
    const float* bout  = (const float*)d_in[8];
    float* out = (float*)d_out;

    // Regions for tmp/h keep their fp32-era SIZE (only half the bytes are used by
    // the fp16 payload) so the bEdges alias (14.2 MB over tmp+h) still fits and
    // the total workspace footprint is unchanged vs the verified layout.
    char* ws = (char*)d_ws;
    int*   rp2       = (int*)ws;   ws += (size_t)(NKEY + 4) * 4;        // 1.6 MB
    int*   col       = (int*)ws;   ws += (size_t)N_EDGES * 4;           // 12.8 MB
    float* dinv      = (float*)ws; ws += (size_t)N_NODES * 4;           // 400 KB
    char*  tmp       = ws;         ws += (size_t)N_NODES * EMB * 4;     // 12.8 MB (6.4 used)
    char*  h         = ws;         ws += (size_t)N_NODES * EMB * 4;     // 12.8 MB (6.4 used)
    int*   bucketCnt = (int*)ws;   ws += 1024;                          // 256 ints
    int*   bucketBase= (int*)ws;   ws += 1024;                          // 256 ints
    unsigned* bEdges = (unsigned*)tmp;   // 14.2 MB alias over tmp+h, dead before transforms

    const int B = 256;
    const int T_g  = (N_NODES + B - 1) / B;              // 391

    init_k<<<1, B, 0, stream>>>(bucketCnt, rp2);
    partition_k<<<PART_NB, PART_THREADS, 0, stream>>>(src, dst, bucketCnt, bEdges);
    bucketbase_k<<<1, 256, 0, stream>>>(bucketCnt, bucketBase);
    fill_k<<<NGROUP, FB, 0, stream>>>(bEdges, bucketCnt, bucketBase, rp2, dinv, col);

    // layer 0 transform (fp16 output)
    transform0_k<<<T_g, B, 0, stream>>>(x, W0, dinv, (h4*)tmp);

    // gathers: layers 0..2 fuse the next transform; layer 3 writes activations only
    gather_mt_k<true ><<<NBLK, B, 0, stream>>>(rp2, col, (const h4*)tmp, dinv, b0,           Ws + 0 * 1024, (h4*)h);
    gather_mt_k<true ><<<NBLK, B, 0, stream>>>(rp2, col, (const h4*)h,   dinv, bs + 0 * EMB, Ws + 1 * 1024, (h4*)tmp);
    gather_mt_k<true ><<<NBLK, B, 0, stream>>>(rp2, col, (const h4*)tmp, dinv, bs + 1 * EMB, Ws + 2 * 1024, (h4*)h);
    gather_mt_k<false><<<NBLK, B, 0, stream>>>(rp2, col, (const h4*)h,   dinv, bs + 2 * EMB, nullptr,       (h4*)tmp);

    pool_head_k<<<NUM_GRAPHS, B, 0, stream>>>((const __half*)tmp, batch, Wout, bout, out);
}

// Round 8
// 365.804 us; speedup vs baseline: 1.0365x; 1.0365x over previous
//
#include <hip/hip_runtime.h>
#include <hip/hip_fp16.h>

#define N_NODES   100000
#define N_EDGES   3200000
#define NUM_GRAPHS 1024
#define F_IN      128
#define EMB       32

#define NRANGE    4
#define RANGE_SZ  25000                    // fp16 rows: 25000*64B = 1.6 MB slice per phase
#define NKEY      (N_NODES * NRANGE)       // 400000 CSR keys

#define NGROUP    256                      // dst buckets
#define GROUP_SZ  391                      // 256*391 = 100096 >= N
#define BCAP      13824                    // mean 12512 + ~11.7 sigma
#define FB        1024                     // fill block threads
#define FILL_ITER 14                       // ceil(BCAP/FB)

#define PART_TILE 8192
#define PART_THREADS 512
#define PART_NB   ((N_EDGES + PART_TILE - 1) / PART_TILE)   // 391

#define NTILE     3125                     // 100000/32 exact; gather grid
#define GCAP      2048                     // per-block col LDS stage (32 nodes, mean 1024, +32 sigma)

// 8-byte half4 payload: node row = 8 quads x 8 B = 64 B = one L2 line per edge
struct __align__(8) h4 { __half2 a, b; };
__device__ inline float4 h4tof4(h4 v) {
    float2 fa = __half22float2(v.a), fb = __half22float2(v.b);
    return make_float4(fa.x, fa.y, fb.x, fb.y);
}
__device__ inline h4 f4toh4(float4 v) {
    h4 r; r.a = __floats2half2_rn(v.x, v.y); r.b = __floats2half2_rn(v.z, v.w); return r;
}

// ---- tiny init: zero bucket counters; rp2 sentinel ----
__global__ void init_k(int* __restrict__ bucketCnt, int* __restrict__ rp2) {
    int i = threadIdx.x;
    if (i < NGROUP) bucketCnt[i] = 0;
    if (i == 0) rp2[NKEY] = N_EDGES;
}

// ---- partition edges into 256 dst-buckets, packed 4B, coalesced nt writes ----
__global__ __launch_bounds__(PART_THREADS) void partition_k(const int* __restrict__ src,
                                                            const int* __restrict__ dst,
                                                            int* __restrict__ bucketCnt,
                                                            unsigned* __restrict__ bEdges) {
    __shared__ unsigned stage[PART_TILE];          // 32 KB
    __shared__ unsigned char bucketOf[PART_TILE];  // 8 KB
    __shared__ int hist[NGROUP];
    __shared__ int lbase[NGROUP + 1];
    __shared__ int gbase[NGROUP];
    __shared__ int sc[NGROUP];
    int t = threadIdx.x;
    int base = blockIdx.x * PART_TILE;
    for (int k = t; k < NGROUP; k += PART_THREADS) hist[k] = 0;
    __syncthreads();
    unsigned val[16]; int bk[16], rk[16];
#pragma unroll
    for (int i = 0; i < 16; ++i) {
        int e = base + i * PART_THREADS + t;
        bk[i] = -1;
        if (e < N_EDGES) {
            unsigned s = (unsigned)__builtin_nontemporal_load(src + e);
            unsigned d = (unsigned)__builtin_nontemporal_load(dst + e);
            int b = (int)(d / GROUP_SZ);
            val[i] = ((d - (unsigned)b * GROUP_SZ) << 17) | s;
            bk[i] = b;
            rk[i] = atomicAdd(&hist[b], 1);            // LDS atomic
        }
    }
    __syncthreads();
    if (t < NGROUP) sc[t] = hist[t];
    __syncthreads();
    for (int off = 1; off < NGROUP; off <<= 1) {
        int v = 0;
        if (t < NGROUP) v = sc[t] + ((t >= off) ? sc[t - off] : 0);
        __syncthreads();
        if (t < NGROUP) sc[t] = v;
        __syncthreads();
    }
    if (t < NGROUP) {
        lbase[t] = sc[t] - hist[t];
        if (hist[t] > 0) gbase[t] = atomicAdd(&bucketCnt[t], hist[t]);
        if (t == NGROUP - 1) lbase[NGROUP] = sc[t];
    }
    __syncthreads();
#pragma unroll
    for (int i = 0; i < 16; ++i)
        if (bk[i] >= 0) {
            int j = lbase[bk[i]] + rk[i];
            stage[j] = val[i];
            bucketOf[j] = (unsigned char)bk[i];
        }
    __syncthreads();
    int total = lbase[NGROUP];
    for (int j = t; j < total; j += PART_THREADS) {
        int b = bucketOf[j];                           // direct lookup
        int off = gbase[b] + (j - lbase[b]);
        if (off < BCAP) __builtin_nontemporal_store(stage[j], &bEdges[(size_t)b * BCAP + off]);
    }
}

// ---- one-off: exclusive scan of 256 bucket counts -> global bucketBase ----
__global__ __launch_bounds__(256) void bucketbase_k(const int* __restrict__ bucketCnt,
                                                    int* __restrict__ bucketBase) {
    __shared__ int l[256];
    int t = threadIdx.x;
    int c = bucketCnt[t]; if (c > BCAP) c = BCAP;
    l[t] = c;
    __syncthreads();
    for (int off = 1; off < 256; off <<= 1) {
        int v = l[t] + ((t >= off) ? l[t - off] : 0);
        __syncthreads();
        l[t] = v;
        __syncthreads();
    }
    bucketBase[t] = l[t] - c;                          // exclusive
}

// ---- per-bucket LDS counting sort with (node, src-range) keys ----
__global__ __launch_bounds__(FB) void fill_k(const unsigned* __restrict__ bEdges,
                                             const int* __restrict__ bucketCnt,
                                             const int* __restrict__ bucketBase,
                                             int* __restrict__ rp2,
                                             float* __restrict__ dinv,
                                             int* __restrict__ col) {
    __shared__ int cur[GROUP_SZ * 4];      // 1564 key cursors
    __shared__ int nodesum[512];
    __shared__ unsigned lout[BCAP];        // 55.3 KB staging
    int b = blockIdx.x, t = threadIdx.x;
    int colBase = bucketBase[b];

    int nb = N_NODES - b * GROUP_SZ; if (nb > GROUP_SZ) nb = GROUP_SZ;
    int nk = nb * 4;
    for (int k = t; k < nk; k += FB) cur[k] = 0;
    __syncthreads();

    int cnt = bucketCnt[b]; if (cnt > BCAP) cnt = BCAP;
    const unsigned* be = bEdges + (size_t)b * BCAP;
    unsigned val[FILL_ITER];
#pragma unroll
    for (int i = 0; i < FILL_ITER; ++i) {
        int idx = i * FB + t;
        val[i] = 0xFFFFFFFFu;
        if (idx < cnt) {
            unsigned v = __builtin_nontemporal_load(be + idx);
            val[i] = v;
            unsigned key = (v >> 17) * NRANGE + (v & 0x1FFFFu) / RANGE_SZ;
            atomicAdd(&cur[key], 1);                   // LDS histogram
        }
    }
    __syncthreads();

    int h0 = 0, h1 = 0, h2 = 0, h3 = 0;
    if (t < nb) {
        h0 = cur[t * 4]; h1 = cur[t * 4 + 1]; h2 = cur[t * 4 + 2]; h3 = cur[t * 4 + 3];
        int dsum = h0 + h1 + h2 + h3;
        nodesum[t] = dsum;
        dinv[b * GROUP_SZ + t] = rsqrtf((float)(dsum + 1));
    } else if (t < 512) nodesum[t] = 0;
    __syncthreads();
    for (int off = 1; off < 512; off <<= 1) {
        int v = 0;
        if (t < 512) v = nodesum[t] + ((t >= off) ? nodesum[t - off] : 0);
        __syncthreads();
        if (t < 512) nodesum[t] = v;
        __syncthreads();
    }
    if (t < nb) {
        int p0 = (t > 0) ? nodesum[t - 1] : 0;
        int p1 = p0 + h0, p2 = p1 + h1, p3 = p2 + h2;
        int kb = (b * GROUP_SZ + t) * 4;
        int4 w; w.x = colBase + p0; w.y = colBase + p1; w.z = colBase + p2; w.w = colBase + p3;
        *(int4*)(rp2 + kb) = w;
        cur[t * 4] = p0; cur[t * 4 + 1] = p1; cur[t * 4 + 2] = p2; cur[t * 4 + 3] = p3;
    }
    __syncthreads();

#pragma unroll
    for (int i = 0; i < FILL_ITER; ++i) {
        unsigned v = val[i];
        if (v != 0xFFFFFFFFu) {
            unsigned key = (v >> 17) * NRANGE + (v & 0x1FFFFu) / RANGE_SZ;
            int slot = atomicAdd(&cur[key], 1);
            lout[slot] = v & 0x1FFFFu;
        }
    }
    __syncthreads();

    for (int i = t; i < cnt; i += FB)
        __builtin_nontemporal_store((int)lout[i], col + colBase + i);
}

// ---- layer 0 transform, register-blocked; writes fp16 payload ----
__global__ __launch_bounds__(256) void transform0_k(const float* __restrict__ x,
                                                    const float* __restrict__ W0,
                                                    const float* __restrict__ dinv,
                                                    h4* __restrict__ tmph) {
    int i = blockIdx.x * blockDim.x + threadIdx.x;   // 100000 threads
    if (i >= (N_NODES / 8) * 8) return;
    int gid = i >> 3, q = i & 7;
    int n0 = gid * 8;
    const float* wq = W0 + q * 4;
    float4 acc[8];
#pragma unroll
    for (int j = 0; j < 8; ++j) acc[j] = make_float4(0.f, 0.f, 0.f, 0.f);
#pragma unroll 2
    for (int kc = 0; kc < F_IN / 4; ++kc) {
        float4 w0 = *(const float4*)(wq + (kc * 4 + 0) * EMB);
        float4 w1 = *(const float4*)(wq + (kc * 4 + 1) * EMB);
        float4 w2 = *(const float4*)(wq + (kc * 4 + 2) * EMB);
        float4 w3 = *(const float4*)(wq + (kc * 4 + 3) * EMB);
#pragma unroll
        for (int j = 0; j < 8; ++j) {
            float4 xv = *(const float4*)(x + (long long)(n0 + j) * F_IN + kc * 4);
            acc[j].x += xv.x * w0.x; acc[j].y += xv.x * w0.y; acc[j].z += xv.x * w0.z; acc[j].w += xv.x * w0.w;
            acc[j].x += xv.y * w1.x; acc[j].y += xv.y * w1.y; acc[j].z += xv.y * w1.z; acc[j].w += xv.y * w1.w;
            acc[j].x += xv.z * w2.x; acc[j].y += xv.z * w2.y; acc[j].z += xv.z * w2.z; acc[j].w += xv.z * w2.w;
            acc[j].x += xv.w * w3.x; acc[j].y += xv.w * w3.y; acc[j].z += xv.w * w3.z; acc[j].w += xv.w * w3.w;
        }
    }
#pragma unroll
    for (int j = 0; j < 8; ++j) {
        float dn = dinv[n0 + j];
        acc[j].x *= dn; acc[j].y *= dn; acc[j].z *= dn; acc[j].w *= dn;
        tmph[(n0 + j) * 8 + q] = f4toh4(acc[j]);
    }
}

// ---- single-tile gather (R1 structure), fp16 payload: 3125 blocks x 256 thr,
// 16.5 KB LDS + low VGPR -> 8 blocks/CU capacity, 32 waves/CU. col span staged
// in LDS (coalesced once); 4 src-range phases; one edge = one 64B L2/L3 line.
// FUSE=1: out = (leaky(agg*dinv+bias) @ W) * dinv    FUSE=0: out = leaky(agg*dinv+bias)
template <bool FUSE>
__global__ __launch_bounds__(256, 8) void gather_k(const int* __restrict__ rp2,
                                                   const int* __restrict__ col,
                                                   const h4* __restrict__ inb,
                                                   const float* __restrict__ dinv,
                                                   const float* __restrict__ bias,
                                                   const float* __restrict__ W,
                                                   h4* __restrict__ outb) {
    __shared__ float4 Wl[256];        // 4 KB
    __shared__ float4 hx[32 * 9];     // 4.5 KB
    __shared__ int colS[GCAP];        // 8 KB
    int t = threadIdx.x;
    int i = blockIdx.x * 256 + t;     // grid exact: 3125 blocks
    int n = i >> 3, q = i & 7, ln = t >> 3;
    int n0 = blockIdx.x * 32;

    if (FUSE) Wl[t] = ((const float4*)W)[t];

    int S = rp2[n0 * 4];
    int E = rp2[n0 * 4 + 128];        // rp2[NKEY] sentinel covers the last block
    int span = E - S;
    bool inL = (span <= GCAP);
    if (inL) {
        for (int j = t; j < span; j += 256)
            colS[j] = __builtin_nontemporal_load(col + S + j);
    }
    __syncthreads();                  // covers colS and Wl

    int4 rpv = *(const int4*)(rp2 + n * 4);
    int rp4  = rp2[n * 4 + 4];
    int begs[5] = {rpv.x, rpv.y, rpv.z, rpv.w, rp4};

    float4 acc = h4tof4(inb[i]);      // self-loop term

    if (inL) {
#pragma unroll
        for (int r = 0; r < NRANGE; ++r) {
            int k = begs[r] - S, end = begs[r + 1] - S;
            for (; k + 8 <= end; k += 8) {            // deep in-flight: 8 gathers
                int c0 = colS[k], c1 = colS[k + 1], c2 = colS[k + 2], c3 = colS[k + 3];
                int c4 = colS[k + 4], c5 = colS[k + 5], c6 = colS[k + 6], c7 = colS[k + 7];
                float4 v0 = h4tof4(inb[c0 * 8 + q]), v1 = h4tof4(inb[c1 * 8 + q]);
                float4 v2 = h4tof4(inb[c2 * 8 + q]), v3 = h4tof4(inb[c3 * 8 + q]);
                float4 v4 = h4tof4(inb[c4 * 8 + q]), v5 = h4tof4(inb[c5 * 8 + q]);
                float4 v6 = h4tof4(inb[c6 * 8 + q]), v7 = h4tof4(inb[c7 * 8 + q]);
                acc.x += (v0.x + v1.x) + (v2.x + v3.x);
                acc.y += (v0.y + v1.y) + (v2.y + v3.y);
                acc.z += (v0.z + v1.z) + (v2.z + v3.z);
                acc.w += (v0.w + v1.w) + (v2.w + v3.w);
                acc.x += (v4.x + v5.x) + (v6.x + v7.x);
                acc.y += (v4.y + v5.y) + (v6.y + v7.y);
                acc.z += (v4.z + v5.z) + (v6.z + v7.z);
                acc.w += (v4.w + v5.w) + (v6.w + v7.w);
            }
            if (k + 4 <= end) {
                int c0 = colS[k], c1 = colS[k + 1], c2 = colS[k + 2], c3 = colS[k + 3];
                float4 v0 = h4tof4(inb[c0 * 8 + q]), v1 = h4tof4(inb[c1 * 8 + q]);
                float4 v2 = h4tof4(inb[c2 * 8 + q]), v3 = h4tof4(inb[c3 * 8 + q]);
                acc.x += (v0.x + v1.x) + (v2.x + v3.x);
                acc.y += (v0.y + v1.y) + (v2.y + v3.y);
                acc.z += (v0.z + v1.z) + (v2.z + v3.z);
                acc.w += (v0.w + v1.w) + (v2.w + v3.w);
                k += 4;
            }
            if (k < end) {                            // single masked-clamped iteration
                int e1 = end - 1;
                int i1 = min(k + 1, e1), i2 = min(k + 2, e1), i3 = min(k + 3, e1);
                float m1 = (k + 1 < end) ? 1.f : 0.f;
                float m2 = (k + 2 < end) ? 1.f : 0.f;
                float m3 = (k + 3 < end) ? 1.f : 0.f;
                int c0 = colS[k], c1 = colS[i1], c2 = colS[i2], c3 = colS[i3];
                float4 v0 = h4tof4(inb[c0 * 8 + q]), v1 = h4tof4(inb[c1 * 8 + q]);
                float4 v2 = h4tof4(inb[c2 * 8 + q]), v3 = h4tof4(inb[c3 * 8 + q]);
                acc.x += (v0.x + m1 * v1.x) + (m2 * v2.x + m3 * v3.x);
                acc.y += (v0.y + m1 * v1.y) + (m2 * v2.y + m3 * v3.y);
                acc.z += (v0.z + m1 * v1.z) + (m2 * v2.z + m3 * v3.z);
                acc.w += (v0.w + m1 * v1.w) + (m2 * v2.w + m3 * v3.w);
            }
        }
    } else {                                          // overflow fallback: global col
#pragma unroll
        for (int r = 0; r < NRANGE; ++r) {
            int k = begs[r], end = begs[r + 1];
            for (; k + 4 <= end; k += 4) {
                int c0 = col[k], c1 = col[k + 1], c2 = col[k + 2], c3 = col[k + 3];
                float4 v0 = h4tof4(inb[c0 * 8 + q]), v1 = h4tof4(inb[c1 * 8 + q]);
                float4 v2 = h4tof4(inb[c2 * 8 + q]), v3 = h4tof4(inb[c3 * 8 + q]);
                acc.x += (v0.x + v1.x) + (v2.x + v3.x);
                acc.y += (v0.y + v1.y) + (v2.y + v3.y);
                acc.z += (v0.z + v1.z) + (v2.z + v3.z);
                acc.w += (v0.w + v1.w) + (v2.w + v3.w);
            }
            if (k < end) {
                int e1 = end - 1;
                int i1 = min(k + 1, e1), i2 = min(k + 2, e1), i3 = min(k + 3, e1);
                float m1 = (k + 1 < end) ? 1.f : 0.f;
                float m2 = (k + 2 < end) ? 1.f : 0.f;
                float m3 = (k + 3 < end) ? 1.f : 0.f;
                int c0 = col[k], c1 = col[i1], c2 = col[i2], c3 = col[i3];
                float4 v0 = h4tof4(inb[c0 * 8 + q]), v1 = h4tof4(inb[c1 * 8 + q]);
                float4 v2 = h4tof4(inb[c2 * 8 + q]), v3 = h4tof4(inb[c3 * 8 + q]);
                acc.x += (v0.x + m1 * v1.x) + (m2 * v2.x + m3 * v3.x);
                acc.y += (v0.y + m1 * v1.y) + (m2 * v2.y + m3 * v3.y);
                acc.z += (v0.z + m1 * v1.z) + (m2 * v2.z + m3 * v3.z);
                acc.w += (v0.w + m1 * v1.w) + (m2 * v2.w + m3 * v3.w);
            }
        }
    }

    float dn = dinv[n];
    float4 bb = ((const float4*)bias)[q];
    float4 rr;
    rr.x = acc.x * dn + bb.x;
    rr.y = acc.y * dn + bb.y;
    rr.z = acc.z * dn + bb.z;
    rr.w = acc.w * dn + bb.w;
    rr.x = rr.x > 0.f ? rr.x : 0.01f * rr.x;
    rr.y = rr.y > 0.f ? rr.y : 0.01f * rr.y;
    rr.z = rr.z > 0.f ? rr.z : 0.01f * rr.z;
    rr.w = rr.w > 0.f ? rr.w : 0.01f * rr.w;

    if (!FUSE) {
        outb[i] = f4toh4(rr);
        return;
    }
    // wave-synchronous h-exchange (lanes ln*8..ln*8+7 are intra-wave)
    hx[ln * 9 + q] = rr;
    __builtin_amdgcn_wave_barrier();
    float4 tq = make_float4(0.f, 0.f, 0.f, 0.f);
#pragma unroll
    for (int kq = 0; kq < 8; ++kq) {
        float4 hv = hx[ln * 9 + kq];
        float4 w0 = Wl[(kq * 4 + 0) * 8 + q];
        float4 w1 = Wl[(kq * 4 + 1) * 8 + q];
        float4 w2 = Wl[(kq * 4 + 2) * 8 + q];
        float4 w3 = Wl[(kq * 4 + 3) * 8 + q];
        tq.x += hv.x * w0.x; tq.y += hv.x * w0.y; tq.z += hv.x * w0.z; tq.w += hv.x * w0.w;
        tq.x += hv.y * w1.x; tq.y += hv.y * w1.y; tq.z += hv.y * w1.z; tq.w += hv.y * w1.w;
        tq.x += hv.z * w2.x; tq.y += hv.z * w2.y; tq.z += hv.z * w2.z; tq.w += hv.z * w2.w;
        tq.x += hv.w * w3.x; tq.y += hv.w * w3.y; tq.z += hv.w * w3.z; tq.w += hv.w * w3.w;
    }
    tq.x *= dn; tq.y *= dn; tq.z *= dn; tq.w *= dn;
    outb[i] = f4toh4(tq);
}

// ---- fused pool + head (batch_index sorted), fp16 input ----
__global__ __launch_bounds__(256) void pool_head_k(const __half* __restrict__ h,
                                                   const int* __restrict__ batch,
                                                   const float* __restrict__ Wout,
                                                   const float* __restrict__ bout,
                                                   float* __restrict__ out) {
    int g = blockIdx.x;
    __shared__ int sbeg, send;
    if (threadIdx.x == 0) {
        int lo = 0, hi = N_NODES;
        while (lo < hi) { int mid = (lo + hi) >> 1; if (batch[mid] < g) lo = mid + 1; else hi = mid; }
        sbeg = lo;
        hi = N_NODES;
        while (lo < hi) { int mid = (lo + hi) >> 1; if (batch[mid] < g + 1) lo = mid + 1; else hi = mid; }
        send = lo;
    }
    __syncthreads();
    int beg = sbeg, end = send;
    int t = threadIdx.x, c = t & 31, r = t >> 5;
    float m = -INFINITY;
    for (int n = beg + r; n < end; n += 8) m = fmaxf(m, __half2float(h[n * EMB + c]));
    __shared__ float red[256];
    red[t] = m;
    __syncthreads();
    if (t < 128) red[t] = fmaxf(red[t], red[t + 128]);
    __syncthreads();
    if (t < 64) red[t] = fmaxf(red[t], red[t + 64]);
    __syncthreads();
    if (t < 32) {
        m = fmaxf(red[t], red[t + 32]);
        out[NUM_GRAPHS + g * EMB + c] = m;
        float p = m * Wout[c];
#pragma unroll
        for (int o = 16; o > 0; o >>= 1) p += __shfl_xor(p, o, 32);
        if (c == 0) out[g] = p + bout[0];
    }
}

extern "C" void kernel_launch(void* const* d_in, const int* in_sizes, int n_in,
                              void* d_out, int out_size, void* d_ws, size_t ws_size,
                              hipStream_t stream) {
    const float* x     = (const float*)d_in[0];
    const int*   ei    = (const int*)d_in[1];
    const int*   src   = ei;
    const int*   dst   = ei + N_EDGES;
    const int*   batch = (const int*)d_in[2];
    const float* W0    = (const float*)d_in[3];
    const float* b0    = (const float*)d_in[4];
    const float* Ws    = (const float*)d_in[5];
    const float* bs    = (const float*)d_in[6];
    const float* Wout  = (const float*)d_in[7];
    const float* bout  = (const float*)d_in[8];
    float* out = (float*)d_out;

    // Regions for tmp/h keep their fp32-era SIZE (only half the bytes are used by
    // the fp16 payload) so the bEdges alias (14.2 MB over tmp+h) still fits and
    // the total workspace footprint is unchanged vs the verified layout.
    char* ws = (char*)d_ws;
    int*   rp2       = (int*)ws;   ws += (size_t)(NKEY + 4) * 4;        // 1.6 MB
    int*   col       = (int*)ws;   ws += (size_t)N_EDGES * 4;           // 12.8 MB
    float* dinv      = (float*)ws; ws += (size_t)N_NODES * 4;           // 400 KB
    char*  tmp       = ws;         ws += (size_t)N_NODES * EMB * 4;     // 12.8 MB (6.4 used)
    char*  h         = ws;         ws += (size_t)N_NODES * EMB * 4;     // 12.8 MB (6.4 used)
    int*   bucketCnt = (int*)ws;   ws += 1024;                          // 256 ints
    int*   bucketBase= (int*)ws;   ws += 1024;                          // 256 ints
    unsigned* bEdges = (unsigned*)tmp;   // 14.2 MB alias over tmp+h, dead before transforms

    const int B = 256;
    const int T_g  = (N_NODES + B - 1) / B;              // 391

    init_k<<<1, B, 0, stream>>>(bucketCnt, rp2);
    partition_k<<<PART_NB, PART_THREADS, 0, stream>>>(src, dst, bucketCnt, bEdges);
    bucketbase_k<<<1, 256, 0, stream>>>(bucketCnt, bucketBase);
    fill_k<<<NGROUP, FB, 0, stream>>>(bEdges, bucketCnt, bucketBase, rp2, dinv, col);

    // layer 0 transform (fp16 output)
    transform0_k<<<T_g, B, 0, stream>>>(x, W0, dinv, (h4*)tmp);

    // gathers: layers 0..2 fuse the next transform; layer 3 writes activations only
    gather_k<true ><<<NTILE, B, 0, stream>>>(rp2, col, (const h4*)tmp, dinv, b0,           Ws + 0 * 1024, (h4*)h);
    gather_k<true ><<<NTILE, B, 0, stream>>>(rp2, col, (const h4*)h,   dinv, bs + 0 * EMB, Ws + 1 * 1024, (h4*)tmp);
    gather_k<true ><<<NTILE, B, 0, stream>>>(rp2, col, (const h4*)tmp, dinv, bs + 1 * EMB, Ws + 2 * 1024, (h4*)h);
    gather_k<false><<<NTILE, B, 0, stream>>>(rp2, col, (const h4*)h,   dinv, bs + 2 * EMB, nullptr,       (h4*)tmp);

    pool_head_k<<<NUM_GRAPHS, B, 0, stream>>>((const __half*)tmp, batch, Wout, bout, out);
}